// Round 13
// baseline (320.568 us; speedup 1.0000x reference)
//
#include <hip/hip_runtime.h>
#include <hip/hip_bf16.h>

// NT-Xent (CLIP) loss, N=16384 D=256 fp32 in, 3 fp32 out.
// loss_vu = mean_i( log(sum_j exp(sim_ij)) - sim_ii ), sim = (v̂·û^T)/T
// Logits bounded by 1/T=14.29 -> no max subtraction needed.
//
// R10-R14: FRAGMENT-MAJOR layout, LDS-free barrier-free K2: 345 -> 196
//     -> 155 -> 153us. R14 lesson: unified reg file (128 VGPR A + 64
//     AGPR acc ~= 192/wave) caps occupancy at 2 waves/SIMD for ANY
//     grid -- occupancy lever dead. MfmaUtil 38%: per-jt epilogue
//     (exp2+sums) is RAW-serial on acc after ks7, and the 2 resident
//     waves stay phase-locked (shared matrix pipe) -> pipe idles every
//     epilogue.
// R15: T15 DOUBLE-PIPELINE. Wave's 64 cols -> two 32-col halves with
//     separate accA/accB (same 64 AGPR total; bb ring 32->16 VGPR).
//     While half-X's 8-ks MFMA phase runs, the PREVIOUS half's epilogue
//     is hand-sliced into the ks steps (4 exp2 + 6 adds per slice, placed
//     inside each sched_barrier region after the MFMA cluster): VALU/
//     TRANS work fills the matrix pipe's drain window. m253 caution
//     noted: their phases were independent; ours is a real RAW break.
//     Gates: VGPR <= ~200 & WRITE ~38MB (no spill), MfmaUtil >= 50%,
//     K2 <= 130us.

#define D_DIM 256

constexpr float INV_T = 1.0f / 0.07f;
constexpr float EXP2_SCALE = 1.44269504088896340736f / 0.07f;  // log2(e)/T

typedef __bf16 bf16x8 __attribute__((ext_vector_type(8)));
typedef float f32x4 __attribute__((ext_vector_type(4)));

// ---------------------------------------------------------------------------
// Kernel 1: L2-normalize fp32 -> bf16 in FRAGMENT-MAJOR layout.
// (R10..R14-verified: absmax 0.) V' pre-scaled by EXP2_SCALE; diag from
// unscaled v,u; zeroes row/colsum and finalize partials.
// ---------------------------------------------------------------------------
__global__ __launch_bounds__(256) void normalize_kernel(
    const float* __restrict__ img, const float* __restrict__ txt,
    __hip_bfloat16* __restrict__ Vf, __hip_bfloat16* __restrict__ Uf,
    float* __restrict__ diagarr, float* __restrict__ rowsum,
    float* __restrict__ colsum, float* __restrict__ partials) {
  const int wave = threadIdx.x >> 6;
  const int lane = threadIdx.x & 63;
  const int sub = lane >> 5;   // 0/1: which of the wave's two rows
  const int pos = lane & 31;   // 8-elem chunk index within the row
  const int row = blockIdx.x * 8 + wave * 2 + sub;
  const size_t base = (size_t)row * D_DIM + pos * 8;

  const float4 i0 = *reinterpret_cast<const float4*>(&img[base]);
  const float4 i1 = *reinterpret_cast<const float4*>(&img[base + 4]);
  const float4 t0 = *reinterpret_cast<const float4*>(&txt[base]);
  const float4 t1 = *reinterpret_cast<const float4*>(&txt[base + 4]);

  float a = i0.x * i0.x + i0.y * i0.y + i0.z * i0.z + i0.w * i0.w +
            i1.x * i1.x + i1.y * i1.y + i1.z * i1.z + i1.w * i1.w;
  float b = t0.x * t0.x + t0.y * t0.y + t0.z * t0.z + t0.w * t0.w +
            t1.x * t1.x + t1.y * t1.y + t1.z * t1.z + t1.w * t1.w;
#pragma unroll
  for (int off = 1; off < 32; off <<= 1) {
    a += __shfl_xor(a, off, 64);
    b += __shfl_xor(b, off, 64);
  }
  const float si = 1.0f / fmaxf(sqrtf(a), 1e-8f);
  const float st = 1.0f / fmaxf(sqrtf(b), 1e-8f);

  const float vs = si * EXP2_SCALE;  // V pre-scaled by log2e/T
  __hip_bfloat16 vb8[8] = {
      __float2bfloat16(i0.x * vs), __float2bfloat16(i0.y * vs),
      __float2bfloat16(i0.z * vs), __float2bfloat16(i0.w * vs),
      __float2bfloat16(i1.x * vs), __float2bfloat16(i1.y * vs),
      __float2bfloat16(i1.z * vs), __float2bfloat16(i1.w * vs)};
  __hip_bfloat16 ub8[8] = {
      __float2bfloat16(t0.x * st), __float2bfloat16(t0.y * st),
      __float2bfloat16(t0.z * st), __float2bfloat16(t0.w * st),
      __float2bfloat16(t1.x * st), __float2bfloat16(t1.y * st),
      __float2bfloat16(t1.z * st), __float2bfloat16(t1.w * st)};

  const int g = row >> 4, l15r = row & 15;
  const int ks = pos >> 2, quad = pos & 3;
  const size_t foff = (size_t)(g * 8 + ks) * 512 + (quad * 16 + l15r) * 8;
  *reinterpret_cast<uint4*>(&Vf[foff]) = *reinterpret_cast<uint4*>(vb8);
  *reinterpret_cast<uint4*>(&Uf[foff]) = *reinterpret_cast<uint4*>(ub8);

  // diag v̂_i·û_i (unscaled)
  float d = (i0.x * si) * (t0.x * st) + (i0.y * si) * (t0.y * st) +
            (i0.z * si) * (t0.z * st) + (i0.w * si) * (t0.w * st) +
            (i1.x * si) * (t1.x * st) + (i1.y * si) * (t1.y * st) +
            (i1.z * si) * (t1.z * st) + (i1.w * si) * (t1.w * st);
#pragma unroll
  for (int off = 1; off < 32; off <<= 1) d += __shfl_xor(d, off, 64);
  if (pos == 0) diagarr[row] = d;

  if (threadIdx.x < 8) {
    rowsum[blockIdx.x * 8 + threadIdx.x] = 0.0f;
    colsum[blockIdx.x * 8 + threadIdx.x] = 0.0f;
  }
  if (blockIdx.x == 0 && threadIdx.x < 4) partials[threadIdx.x] = 0.0f;
}

// ---------------------------------------------------------------------------
// Kernel 2: barrier-free streaming MFMA GEMM + online exp2 sums, T15
// double-pipeline. Block b: row-strip rb = b>>1 (64 rows), col-half
// ch = b&1 (8192 cols = 16 jt of 512). 8 waves; wave w covers 64 cols
// per jt, processed as two 32-col PHASES (h=0,1) with accA/accB.
// Each PHASE: 8 ks x {prefetch 2 B-frags for ks+1 | SB(0) | 8 MFMA |
// epi-slice of the OTHER acc (4 exp2 + sums)}. Epilogue thus overlaps
// the matrix pipe's drain. bb ring bb[2][2]. A a[4][8] resident.
// acc layout (verified): row = mi*16 + quad*4 + r, col = ni*16 + l15.
// ---------------------------------------------------------------------------
__global__ __launch_bounds__(512, 2) void gemm_lse_kernel(
    const __hip_bfloat16* __restrict__ Vf, const __hip_bfloat16* __restrict__ Uf,
    float* __restrict__ rowsum, float* __restrict__ colsum, int n) {
  __shared__ float colbuf[8192];  // 32 KB; each entry written exactly once

  const int tid = threadIdx.x;
  const int lane = tid & 63;
  const int w = tid >> 6;        // 0..7
  const int quad = lane >> 4;
  const int l15 = lane & 15;
  const int rb = blockIdx.x >> 1;   // row strip
  const int ch = blockIdx.x & 1;    // col half (constant per XCD)
  const int njt = n >> 10;          // j-tiles per block (16)

  // A fragments for rows [rb*64, +64): groups 4rb..4rb+3, all K, once.
  bf16x8 a[4][8];
#pragma unroll
  for (int mi = 0; mi < 4; ++mi)
#pragma unroll
    for (int ks = 0; ks < 8; ++ks)
      a[mi][ks] = *reinterpret_cast<const bf16x8*>(
          Vf + (size_t)((4 * rb + mi) * 8 + ks) * 512 + lane * 8);

  float rs[4][4] = {};  // rowsum partials (mi, r), all phases

  // B addressing: group g -> frags at (g*8+ks)*512 + lane*8.
  const __hip_bfloat16* Ub = Uf + lane * 8;
  const size_t PH = (size_t)8 * 512;  // elems per group's frag block
  const size_t gbase0 = ((size_t)ch * 512 + w * 4) * PH;
  // goff(jl,h) = gbase0 + (jl*32 + h*2)*PH ; ni=1 adds PH.

  bf16x8 bb[2][2];
  f32x4 accA[4][2], accB[4][2];
  const f32x4 fz = {};

  // PHASE: compute ACC over groups at GCUR (2 ni), prefetch GNEXT's ks0
  // at ks7; if EPI, slice the other acc's epilogue into the ks steps.
#define PHASE(ACC, GCUR, GNEXT, EPI, EACC, CBASE)                           \
  {                                                                         \
    float ecs0 = 0.f, ecs1 = 0.f;                                           \
    _Pragma("unroll") for (int ks = 0; ks < 8; ++ks) {                      \
      {                                                                     \
        const size_t pg = (ks < 7) ? (GCUR) : (GNEXT);                      \
        const int pks = (ks < 7) ? ks + 1 : 0;                              \
        bb[(ks + 1) & 1][0] = *reinterpret_cast<const bf16x8*>(             \
            Ub + pg + (size_t)pks * 512);                                   \
        bb[(ks + 1) & 1][1] = *reinterpret_cast<const bf16x8*>(             \
            Ub + pg + PH + (size_t)pks * 512);                              \
        __builtin_amdgcn_sched_barrier(0);                                  \
      }                                                                     \
      _Pragma("unroll") for (int mi = 0; mi < 4; ++mi) {                    \
        ACC[mi][0] = __builtin_amdgcn_mfma_f32_16x16x32_bf16(               \
            a[mi][ks], bb[ks & 1][0], (ks == 0) ? fz : ACC[mi][0], 0, 0, 0);\
        ACC[mi][1] = __builtin_amdgcn_mfma_f32_16x16x32_bf16(               \
            a[mi][ks], bb[ks & 1][1], (ks == 0) ? fz : ACC[mi][1], 0, 0, 0);\
      }                                                                     \
      if (EPI) {                                                            \
        const int emi = ks >> 1, er = (ks & 1) * 2;                         \
        _Pragma("unroll") for (int rr = 0; rr < 2; ++rr) {                  \
          const float e0 = __builtin_amdgcn_exp2f(EACC[emi][0][er + rr]);   \
          const float e1 = __builtin_amdgcn_exp2f(EACC[emi][1][er + rr]);   \
          rs[emi][er + rr] += e0 + e1;                                      \
          ecs0 += e0;                                                       \
          ecs1 += e1;                                                       \
        }                                                                   \
      }                                                                     \
    }                                                                       \
    if (EPI) {                                                              \
      ecs0 += __shfl_xor(ecs0, 16, 64);                                     \
      ecs0 += __shfl_xor(ecs0, 32, 64);                                     \
      ecs1 += __shfl_xor(ecs1, 16, 64);                                     \
      ecs1 += __shfl_xor(ecs1, 32, 64);                                     \
      if (lane < 16) {                                                      \
        colbuf[(CBASE) + l15] = ecs0;                                       \
        colbuf[(CBASE) + 16 + l15] = ecs1;                                  \
      }                                                                     \
    }                                                                       \
  }

  // prologue: load phase(0,0) ks0 into bank 0.
  bb[0][0] = *reinterpret_cast<const bf16x8*>(Ub + gbase0);
  bb[0][1] = *reinterpret_cast<const bf16x8*>(Ub + gbase0 + PH);

  // phase (0,0) -> accA, no epilogue yet.
  PHASE(accA, gbase0, gbase0 + 2 * PH, 0, accA, 0);

  for (int jl = 0; jl < njt; ++jl) {
    const size_t g0 = gbase0 + ((size_t)jl * 32) * PH;        // (jl, h=0)
    const size_t g1 = g0 + 2 * PH;                             // (jl, h=1)
    const size_t gn0 = (jl < njt - 1) ? g0 + 32 * PH : g1;     // (jl+1, 0)
    const size_t gn1 = gn0 + 2 * PH;                           // (jl+1, 1)
    const int cb = jl * 512 + w * 64;

    // compute (jl,1) -> accB, epilogue accA = (jl,0)
    PHASE(accB, g1, gn0, 1, accA, cb);
    if (jl < njt - 1) {
      // compute (jl+1,0) -> accA, epilogue accB = (jl,1)
      PHASE(accA, gn0, gn1, 1, accB, cb + 32);
    }
  }

  // standalone final epilogue: accB = (njt-1, 1).
  {
    float ecs0 = 0.f, ecs1 = 0.f;
#pragma unroll
    for (int mi = 0; mi < 4; ++mi)
#pragma unroll
      for (int r = 0; r < 4; ++r) {
        const float e0 = __builtin_amdgcn_exp2f(accB[mi][0][r]);
        const float e1 = __builtin_amdgcn_exp2f(accB[mi][1][r]);
        rs[mi][r] += e0 + e1;
        ecs0 += e0;
        ecs1 += e1;
      }
    ecs0 += __shfl_xor(ecs0, 16, 64);
    ecs0 += __shfl_xor(ecs0, 32, 64);
    ecs1 += __shfl_xor(ecs1, 16, 64);
    ecs1 += __shfl_xor(ecs1, 32, 64);
    const int cb = (njt - 1) * 512 + w * 64 + 32;
    if (lane < 16) {
      colbuf[cb + l15] = ecs0;
      colbuf[cb + 16 + l15] = ecs1;
    }
  }

  // flush colsum once: coalesced atomics, off the critical path.
  __syncthreads();
  const int colbase = ch * (n >> 1);
  for (int i = tid; i < (n >> 1); i += 512)
    atomicAdd(&colsum[colbase + i], colbuf[i]);

  // final rowsum: reduce over the 16 l15 lanes; waves+col-halves meet
  // via atomics.
#pragma unroll
  for (int mi = 0; mi < 4; ++mi)
#pragma unroll
    for (int r = 0; r < 4; ++r) {
      float v = rs[mi][r];
      v += __shfl_xor(v, 1, 64);
      v += __shfl_xor(v, 2, 64);
      v += __shfl_xor(v, 4, 64);
      v += __shfl_xor(v, 8, 64);
      if (l15 == 0)
        atomicAdd(&rowsum[rb * 64 + mi * 16 + quad * 4 + r], v);
    }
}

// ---------------------------------------------------------------------------
// Kernel 3a: parallel partial reduction of log(rowsum), log(colsum), diag.
// ---------------------------------------------------------------------------
__global__ __launch_bounds__(256) void finalize_partial(
    const float* __restrict__ rowsum, const float* __restrict__ colsum,
    const float* __restrict__ diagarr, float* __restrict__ partials, int n) {
  float sr = 0.0f, sc = 0.0f, sd = 0.0f;
  for (int i = blockIdx.x * 256 + threadIdx.x; i < n; i += gridDim.x * 256) {
    sr += __logf(rowsum[i]);
    sc += __logf(colsum[i]);
    sd += diagarr[i];
  }
#pragma unroll
  for (int off = 1; off < 64; off <<= 1) {
    sr += __shfl_xor(sr, off, 64);
    sc += __shfl_xor(sc, off, 64);
    sd += __shfl_xor(sd, off, 64);
  }
  if ((threadIdx.x & 63) == 0) {
    atomicAdd(&partials[0], sr);
    atomicAdd(&partials[1], sc);
    atomicAdd(&partials[2], sd);
  }
}

// ---------------------------------------------------------------------------
// Kernel 3b: final 3-float output from the totals.
// ---------------------------------------------------------------------------
__global__ void finalize_final(const float* __restrict__ partials,
                               float* __restrict__ out, int n) {
  const float invN = 1.0f / (float)n;
  const float dm = partials[2] * INV_T * invN;  // mean diag logit
  const float lvu = partials[0] * invN - dm;
  const float luv = partials[1] * invN - dm;
  out[0] = 0.5f * lvu + 0.5f * luv;  // WEIGHT = 0.5
  out[1] = lvu;
  out[2] = luv;
}

extern "C" void kernel_launch(void* const* d_in, const int* in_sizes, int n_in,
                              void* d_out, int out_size, void* d_ws, size_t ws_size,
                              hipStream_t stream) {
  const float* img = (const float*)d_in[0];
  const float* txt = (const float*)d_in[1];
  float* out = (float*)d_out;
  const int N = in_sizes[0] / D_DIM;  // 16384

  char* ws = (char*)d_ws;
  __hip_bfloat16* Vf = (__hip_bfloat16*)ws;                             // 8MB
  __hip_bfloat16* Uf = (__hip_bfloat16*)(ws + (size_t)N * D_DIM * 2);   // 8MB
  float* rowsum = (float*)(ws + (size_t)N * D_DIM * 4);
  float* colsum = rowsum + N;
  float* diagarr = colsum + N;
  float* partials = diagarr + N;  // 4 floats

  // rowsum/colsum/partials zeroed inside normalize_kernel
  normalize_kernel<<<N / 8, 256, 0, stream>>>(img, txt, Vf, Uf, diagarr,
                                              rowsum, colsum, partials);

  gemm_lse_kernel<<<N / 32, 512, 0, stream>>>(Vf, Uf, rowsum, colsum, N);

  finalize_partial<<<64, 256, 0, stream>>>(rowsum, colsum, diagarr, partials,
                                           N);
  finalize_final<<<1, 1, 0, stream>>>(partials, out, N);
}

// Round 14
// 243.085 us; speedup vs baseline: 1.3187x; 1.3187x over previous
//
#include <hip/hip_runtime.h>
#include <hip/hip_bf16.h>

// NT-Xent (CLIP) loss, N=16384 D=256 fp32 in, 3 fp32 out.
// loss_vu = mean_i( log(sum_j exp(sim_ij)) - sim_ii ), sim = (v̂·û^T)/T
// Logits bounded by 1/T=14.29 -> no max subtraction needed.
//
// R10-R14: FRAGMENT-MAJOR layout, LDS-free barrier-free K2:
//     345 -> 196 -> 155 -> 153us. Occupancy pinned at 2 waves/SIMD by the
//     unified reg file (A 128 VGPR + acc 64 AGPR) -- lever dead (R14).
// R15: T15 epilogue-slicing -- REGRESSED (254us): WRITE 38->61MB = spill.
//     m253's no-transfer verdict confirmed. Reverted.
// R16: 32x32x16 MFMA (pre-committed fallback). 4061 vs 3378 FLOP/CU-cyc
//     (m119/m06): matrix-pipe demand 66->55us; MFMA instr count HALVES
//     (64/wave-jt) -> half the issue/waitcnt boundaries in the ks loop.
//     K1 repacks to the 32x32 operand order (we own the layout):
//       A/B frag (g32,ks16): lane = h*32+m holds row m, k = ks*16+h*8..+8
//       C/D: col = lane&31, row = (reg&3)+8*(reg>>2)+4*(lane>>5)  [m74]
//     Regs ~neutral: A 128, acc 64 AGPR, bb 32->16, rs 16->32.
//     Gates: absmax 0 (layout), WRITE ~38MB (no spill), K2 <= 140us.

#define D_DIM 256

constexpr float INV_T = 1.0f / 0.07f;
constexpr float EXP2_SCALE = 1.44269504088896340736f / 0.07f;  // log2(e)/T

typedef __bf16 bf16x8 __attribute__((ext_vector_type(8)));
typedef float f32x16 __attribute__((ext_vector_type(16)));

// ---------------------------------------------------------------------------
// Kernel 1: L2-normalize fp32 -> bf16, packed in 32x32x16-fragment order.
// One wave = 2 rows: lane = sub(1)|pos(5); lane handles 8 elems
// [pos*8,+8) of row (blk*8 + wave*2 + sub). Norm-reduce over the 32-lane
// half. Fragment write: row r -> group g32=r>>5, slot m=r&31; chunk pos
// -> ks=pos>>1, h=pos&1; elem offset (g32*16+ks)*512 + (h*32+m)*8.
// V' pre-scaled by EXP2_SCALE; diag from unscaled v,u; zeroes row/colsum
// and finalize partials.
// ---------------------------------------------------------------------------
__global__ __launch_bounds__(256) void normalize_kernel(
    const float* __restrict__ img, const float* __restrict__ txt,
    __hip_bfloat16* __restrict__ Vf, __hip_bfloat16* __restrict__ Uf,
    float* __restrict__ diagarr, float* __restrict__ rowsum,
    float* __restrict__ colsum, float* __restrict__ partials) {
  const int wave = threadIdx.x >> 6;
  const int lane = threadIdx.x & 63;
  const int sub = lane >> 5;   // 0/1: which of the wave's two rows
  const int pos = lane & 31;   // 8-elem chunk index within the row
  const int row = blockIdx.x * 8 + wave * 2 + sub;
  const size_t base = (size_t)row * D_DIM + pos * 8;

  const float4 i0 = *reinterpret_cast<const float4*>(&img[base]);
  const float4 i1 = *reinterpret_cast<const float4*>(&img[base + 4]);
  const float4 t0 = *reinterpret_cast<const float4*>(&txt[base]);
  const float4 t1 = *reinterpret_cast<const float4*>(&txt[base + 4]);

  float a = i0.x * i0.x + i0.y * i0.y + i0.z * i0.z + i0.w * i0.w +
            i1.x * i1.x + i1.y * i1.y + i1.z * i1.z + i1.w * i1.w;
  float b = t0.x * t0.x + t0.y * t0.y + t0.z * t0.z + t0.w * t0.w +
            t1.x * t1.x + t1.y * t1.y + t1.z * t1.z + t1.w * t1.w;
#pragma unroll
  for (int off = 1; off < 32; off <<= 1) {
    a += __shfl_xor(a, off, 64);
    b += __shfl_xor(b, off, 64);
  }
  const float si = 1.0f / fmaxf(sqrtf(a), 1e-8f);
  const float st = 1.0f / fmaxf(sqrtf(b), 1e-8f);

  const float vs = si * EXP2_SCALE;  // V pre-scaled by log2e/T
  __hip_bfloat16 vb8[8] = {
      __float2bfloat16(i0.x * vs), __float2bfloat16(i0.y * vs),
      __float2bfloat16(i0.z * vs), __float2bfloat16(i0.w * vs),
      __float2bfloat16(i1.x * vs), __float2bfloat16(i1.y * vs),
      __float2bfloat16(i1.z * vs), __float2bfloat16(i1.w * vs)};
  __hip_bfloat16 ub8[8] = {
      __float2bfloat16(t0.x * st), __float2bfloat16(t0.y * st),
      __float2bfloat16(t0.z * st), __float2bfloat16(t0.w * st),
      __float2bfloat16(t1.x * st), __float2bfloat16(t1.y * st),
      __float2bfloat16(t1.z * st), __float2bfloat16(t1.w * st)};

  const int g32 = row >> 5, m = row & 31;
  const int ks = pos >> 1, h = pos & 1;
  const size_t foff = (size_t)(g32 * 16 + ks) * 512 + (h * 32 + m) * 8;
  *reinterpret_cast<uint4*>(&Vf[foff]) = *reinterpret_cast<uint4*>(vb8);
  *reinterpret_cast<uint4*>(&Uf[foff]) = *reinterpret_cast<uint4*>(ub8);

  // diag v̂_i·û_i (unscaled)
  float d = (i0.x * si) * (t0.x * st) + (i0.y * si) * (t0.y * st) +
            (i0.z * si) * (t0.z * st) + (i0.w * si) * (t0.w * st) +
            (i1.x * si) * (t1.x * st) + (i1.y * si) * (t1.y * st) +
            (i1.z * si) * (t1.z * st) + (i1.w * si) * (t1.w * st);
#pragma unroll
  for (int off = 1; off < 32; off <<= 1) d += __shfl_xor(d, off, 64);
  if (pos == 0) diagarr[row] = d;

  if (threadIdx.x < 8) {
    rowsum[blockIdx.x * 8 + threadIdx.x] = 0.0f;
    colsum[blockIdx.x * 8 + threadIdx.x] = 0.0f;
  }
  if (blockIdx.x == 0 && threadIdx.x < 4) partials[threadIdx.x] = 0.0f;
}

// ---------------------------------------------------------------------------
// Kernel 2: barrier-free streaming 32x32x16-MFMA GEMM + online exp2 sums.
// Block b: row-strip rb = b>>1 (64 rows = groups 2rb,2rb+1), col-half
// ch = b&1 (8192 cols = 16 jt of 512). 8 waves; wave w covers cols
// [jt*512 + w*64, +64) = col-groups {jt*16 + w*2, +1}. A a[2][16]
// (128 VGPR) resident. B: depth-2 ring bb[2][2]; at ks issue load(ks+1)
// into the other bank, sched_barrier(0) pin, consume bank ks&1; ks=15
// prefetches next jt's ks0 (covered by the per-jt epilogue).
// colsum: LDS colbuf[8192] single-writer stores, coalesced atomic flush.
// C/D (m74-verified): col = lane&31, row = (reg&3)+8*(reg>>2)+4*(lane>>5).
// ---------------------------------------------------------------------------
__global__ __launch_bounds__(512, 2) void gemm_lse_kernel(
    const __hip_bfloat16* __restrict__ Vf, const __hip_bfloat16* __restrict__ Uf,
    float* __restrict__ rowsum, float* __restrict__ colsum, int n) {
  __shared__ float colbuf[8192];  // 32 KB; each entry written exactly once

  const int tid = threadIdx.x;
  const int lane = tid & 63;
  const int w = tid >> 6;        // 0..7
  const int l31 = lane & 31;
  const int h = lane >> 5;
  const int rb = blockIdx.x >> 1;   // row strip
  const int ch = blockIdx.x & 1;    // col half (constant per XCD)
  const int njt = n >> 10;          // j-tiles per block (16)

  // A fragments for rows [rb*64, +64): groups 2rb, 2rb+1, all 16 k-slices.
  bf16x8 a[2][16];
#pragma unroll
  for (int mi = 0; mi < 2; ++mi)
#pragma unroll
    for (int ks = 0; ks < 16; ++ks)
      a[mi][ks] = *reinterpret_cast<const bf16x8*>(
          Vf + (size_t)((2 * rb + mi) * 16 + ks) * 512 + lane * 8);

  float rs[2][16] = {};  // rowsum partials: row = mi*32+(reg&3)+8*(reg>>2)+4h

  // B addressing: col-group cg -> frags at (cg*16+ks)*512 + lane*8.
  const __hip_bfloat16* Ub = Uf + lane * 8;
  const size_t PH = (size_t)16 * 512;  // elems per col-group frag block
  const size_t gbase0 = ((size_t)ch * 256 + w * 2) * PH;
  const size_t JSTRIDE = 16 * PH;      // per-jt stride (16 col-groups)

  bf16x8 bb[2][2];
  f32x16 acc[2][2];

  // prologue: jt0 ks0 -> bank 0.
  bb[0][0] = *reinterpret_cast<const bf16x8*>(Ub + gbase0);
  bb[0][1] = *reinterpret_cast<const bf16x8*>(Ub + gbase0 + PH);

  for (int jl = 0; jl < njt; ++jl) {
    const size_t jb = gbase0 + (size_t)jl * JSTRIDE;
    const size_t jbn = (jl < njt - 1) ? jb + JSTRIDE : gbase0;  // wrap
#pragma unroll
    for (int mi = 0; mi < 2; ++mi)
#pragma unroll
      for (int ni = 0; ni < 2; ++ni)
        acc[mi][ni] = (f32x16){};

#pragma unroll
    for (int ks = 0; ks < 16; ++ks) {
      // issue load for step ks+1 into the other bank (free since ks-1)
      {
        const size_t pjb = (ks < 15) ? jb : jbn;
        const int pks = (ks < 15) ? ks + 1 : 0;
        bb[(ks + 1) & 1][0] = *reinterpret_cast<const bf16x8*>(
            Ub + pjb + (size_t)pks * 512);
        bb[(ks + 1) & 1][1] = *reinterpret_cast<const bf16x8*>(
            Ub + pjb + PH + (size_t)pks * 512);
        __builtin_amdgcn_sched_barrier(0);
      }
      // consume bank ks&1
#pragma unroll
      for (int mi = 0; mi < 2; ++mi)
#pragma unroll
        for (int ni = 0; ni < 2; ++ni)
          acc[mi][ni] = __builtin_amdgcn_mfma_f32_32x32x16_bf16(
              a[mi][ks], bb[ks & 1][ni], acc[mi][ni], 0, 0, 0);
    }

    // per-jt epilogue: exp2, rowsum regs, colsum -> LDS. Also the latency
    // cover for the next jt's ks0 prefetch.
    float cs0 = 0.f, cs1 = 0.f;
#pragma unroll
    for (int mi = 0; mi < 2; ++mi)
#pragma unroll
      for (int reg = 0; reg < 16; ++reg) {
        const float e0 = __builtin_amdgcn_exp2f(acc[mi][0][reg]);
        const float e1 = __builtin_amdgcn_exp2f(acc[mi][1][reg]);
        rs[mi][reg] += e0 + e1;
        cs0 += e0;
        cs1 += e1;
      }
    // combine the two k-halves' row contributions: lanes l and l^32 share
    // the same column (col = lane&31).
    cs0 += __shfl_xor(cs0, 32, 64);
    cs1 += __shfl_xor(cs1, 32, 64);
    if (lane < 32) {
      colbuf[jl * 512 + w * 64 + l31] = cs0;        // ni=0 cols
      colbuf[jl * 512 + w * 64 + 32 + l31] = cs1;   // ni=1 cols
    }
  }

  // flush colsum once: coalesced atomics, off the critical path.
  __syncthreads();
  const int colbase = ch * (n >> 1);
  for (int i = tid; i < (n >> 1); i += 512)
    atomicAdd(&colsum[colbase + i], colbuf[i]);

  // final rowsum: reduce over the 32 column-lanes; lane 0 (h=0) and
  // lane 32 (h=1) hold distinct row sets -> both write.
#pragma unroll
  for (int mi = 0; mi < 2; ++mi)
#pragma unroll
    for (int reg = 0; reg < 16; ++reg) {
      float v = rs[mi][reg];
      v += __shfl_xor(v, 1, 64);
      v += __shfl_xor(v, 2, 64);
      v += __shfl_xor(v, 4, 64);
      v += __shfl_xor(v, 8, 64);
      v += __shfl_xor(v, 16, 64);
      if (l31 == 0) {
        const int r = (reg & 3) + 8 * (reg >> 2) + 4 * h;
        atomicAdd(&rowsum[rb * 64 + mi * 32 + r], v);
      }
    }
}

// ---------------------------------------------------------------------------
// Kernel 3a: parallel partial reduction of log(rowsum), log(colsum), diag.
// ---------------------------------------------------------------------------
__global__ __launch_bounds__(256) void finalize_partial(
    const float* __restrict__ rowsum, const float* __restrict__ colsum,
    const float* __restrict__ diagarr, float* __restrict__ partials, int n) {
  float sr = 0.0f, sc = 0.0f, sd = 0.0f;
  for (int i = blockIdx.x * 256 + threadIdx.x; i < n; i += gridDim.x * 256) {
    sr += __logf(rowsum[i]);
    sc += __logf(colsum[i]);
    sd += diagarr[i];
  }
#pragma unroll
  for (int off = 1; off < 64; off <<= 1) {
    sr += __shfl_xor(sr, off, 64);
    sc += __shfl_xor(sc, off, 64);
    sd += __shfl_xor(sd, off, 64);
  }
  if ((threadIdx.x & 63) == 0) {
    atomicAdd(&partials[0], sr);
    atomicAdd(&partials[1], sc);
    atomicAdd(&partials[2], sd);
  }
}

// ---------------------------------------------------------------------------
// Kernel 3b: final 3-float output from the totals.
// ---------------------------------------------------------------------------
__global__ void finalize_final(const float* __restrict__ partials,
                               float* __restrict__ out, int n) {
  const float invN = 1.0f / (float)n;
  const float dm = partials[2] * INV_T * invN;  // mean diag logit
  const float lvu = partials[0] * invN - dm;
  const float luv = partials[1] * invN - dm;
  out[0] = 0.5f * lvu + 0.5f * luv;  // WEIGHT = 0.5
  out[1] = lvu;
  out[2] = luv;
}

extern "C" void kernel_launch(void* const* d_in, const int* in_sizes, int n_in,
                              void* d_out, int out_size, void* d_ws, size_t ws_size,
                              hipStream_t stream) {
  const float* img = (const float*)d_in[0];
  const float* txt = (const float*)d_in[1];
  float* out = (float*)d_out;
  const int N = in_sizes[0] / D_DIM;  // 16384

  char* ws = (char*)d_ws;
  __hip_bfloat16* Vf = (__hip_bfloat16*)ws;                             // 8MB
  __hip_bfloat16* Uf = (__hip_bfloat16*)(ws + (size_t)N * D_DIM * 2);   // 8MB
  float* rowsum = (float*)(ws + (size_t)N * D_DIM * 4);
  float* colsum = rowsum + N;
  float* diagarr = colsum + N;
  float* partials = diagarr + N;  // 4 floats

  // rowsum/colsum/partials zeroed inside normalize_kernel
  normalize_kernel<<<N / 8, 256, 0, stream>>>(img, txt, Vf, Uf, diagarr,
                                              rowsum, colsum, partials);

  gemm_lse_kernel<<<N / 32, 512, 0, stream>>>(Vf, Uf, rowsum, colsum, N);

  finalize_partial<<<64, 256, 0, stream>>>(rowsum, colsum, diagarr, partials,
                                           N);
  finalize_final<<<1, 1, 0, stream>>>(partials, out, N);
}